// Round 2
// baseline (1442.581 us; speedup 1.0000x reference)
//
#include <hip/hip_runtime.h>
#include <hip/hip_bf16.h>

// TGCN graph convolution: out = (L @ [inputs|hidden]) @ W + b
// N=16384, B=2, F=32, G=16, OUT=16.  Dominant cost: stream L (1.07 GB fp32).
// Round 2: barrier-free register-direct MFMA GEMM. No LDS in the main loop:
// A fragments (8 consecutive fp32/lane) and B fragments (8 consecutive
// bf16/lane) load straight from global into registers, 1-iter software
// prefetch, per-rowgroup k-rotation to break 64KB-stride DRAM hotspots.
// Workspace: Xt bf16 3 MB @ ws+0, Cp fp32 partials 25.2 MB @ ws+4MB.

#define NN   16384
#define FF   32
#define GG   16
#define OUTD 16
#define C96  96
#define SPLITK 4
#define KCHUNK (NN / SPLITK)   // 4096
#define KIT    (KCHUNK / 32)   // 128 iters of K=32

typedef __attribute__((ext_vector_type(8))) short short8;
typedef __attribute__((ext_vector_type(4))) float f32x4;

__device__ __forceinline__ unsigned short f2bf(float f) {
  __hip_bfloat16 h = __float2bfloat16(f);
  return __builtin_bit_cast(unsigned short, h);
}

// ---------------------------------------------------------------------------
// Prep: Xt[c][n] bf16, c = b*48 + (f | 32+g), via LDS transpose (coalesced).
// ---------------------------------------------------------------------------
__global__ __launch_bounds__(256) void prep_xt(const float* __restrict__ inp,
                                               const float* __restrict__ hid,
                                               unsigned short* __restrict__ xt) {
  __shared__ float lds_cat[C96][64];
  const int tid = threadIdx.x;
  const int n0 = blockIdx.x * 64;

#pragma unroll
  for (int r = 0; r < 2; ++r) {
    int fi = tid + r * 256;       // 0..511
    int n = fi >> 3;
    int f4 = fi & 7;
#pragma unroll
    for (int b = 0; b < 2; ++b) {
      const float4* src = (const float4*)(inp + ((size_t)b * NN + (n0 + n)) * FF) + f4;
      float4 v = *src;
      int c = b * 48 + f4 * 4;
      lds_cat[c + 0][n] = v.x;
      lds_cat[c + 1][n] = v.y;
      lds_cat[c + 2][n] = v.z;
      lds_cat[c + 3][n] = v.w;
    }
  }
  {
    int n = tid >> 2;
    int g4 = tid & 3;
#pragma unroll
    for (int b = 0; b < 2; ++b) {
      const float4* src = (const float4*)(hid + ((size_t)b * NN + (n0 + n)) * GG) + g4;
      float4 v = *src;
      int c = b * 48 + 32 + g4 * 4;
      lds_cat[c + 0][n] = v.x;
      lds_cat[c + 1][n] = v.y;
      lds_cat[c + 2][n] = v.z;
      lds_cat[c + 3][n] = v.w;
    }
  }
  __syncthreads();
#pragma unroll
  for (int r = 0; r < 3; ++r) {
    int u = tid + r * 256;
    int c = u >> 3;
    int nn = (u & 7) * 8;
    short8 o;
#pragma unroll
    for (int j = 0; j < 8; ++j) o[j] = (short)f2bf(lds_cat[c][nn + j]);
    *(short8*)(xt + (size_t)c * NN + n0 + nn) = o;
  }
}

// ---------------------------------------------------------------------------
// Main: Cp[sp][m][c] partial (L @ X) over k in [sp*4096, (sp+1)*4096).
// Barrier-free: each wave owns 32 rows x 96 cols (2x6 tiles of 16x16x32).
// A-frag: lane(m,quad) reads L[row][k0+quad*8 .. +7] (8 fp32, 32B).
// B-frag: lane(c,quad) reads Xt[c][k0+quad*8 .. +7]  (8 bf16, 16B).
// 1-iter register prefetch; k-loop rotated by rowgroup to spread DRAM pages.
// ---------------------------------------------------------------------------
__global__ __launch_bounds__(256) void spmm_main(const float* __restrict__ L,
                                                 const unsigned short* __restrict__ xt,
                                                 float* __restrict__ cp) {
  const int tid = threadIdx.x;
  const int wave = tid >> 6;
  const int lane = tid & 63;
  const int m = lane & 15;
  const int quad = lane >> 4;
  const int bx = blockIdx.x;
  const int sp = bx & 3;          // split index -> XCD-aligned (bx%8 cycles sp)
  const int rg = bx >> 2;         // rowgroup: 128 rows
  const int m0 = rg * 128 + wave * 32;
  const int kb = sp * KCHUNK;
  const int phase = (rg * 29) & (KIT - 1);

  const float* arow0 = L + (size_t)(m0 + m) * NN + kb + quad * 8;
  const float* arow1 = arow0 + (size_t)16 * NN;
  const unsigned short* brow[6];
#pragma unroll
  for (int t = 0; t < 6; ++t)
    brow[t] = xt + (size_t)(t * 16 + m) * NN + kb + quad * 8;

  f32x4 acc[2][6];
#pragma unroll
  for (int i = 0; i < 2; ++i)
#pragma unroll
    for (int t = 0; t < 6; ++t) acc[i][t] = (f32x4){0.f, 0.f, 0.f, 0.f};

  // prefetch iter 0
  int k0 = phase * 32;
  float4 a0n = *(const float4*)(arow0 + k0);
  float4 a1n = *(const float4*)(arow0 + k0 + 4);
  float4 a2n = *(const float4*)(arow1 + k0);
  float4 a3n = *(const float4*)(arow1 + k0 + 4);
  short8 bn[6];
#pragma unroll
  for (int t = 0; t < 6; ++t) bn[t] = *(const short8*)(brow[t] + k0);

  for (int it = 0; it < KIT; ++it) {
    float4 a0 = a0n, a1 = a1n, a2 = a2n, a3 = a3n;
    short8 bc[6];
#pragma unroll
    for (int t = 0; t < 6; ++t) bc[t] = bn[t];

    int kn = ((it + 1 + phase) & (KIT - 1)) * 32;   // wraps; re-read harmless
    a0n = *(const float4*)(arow0 + kn);
    a1n = *(const float4*)(arow0 + kn + 4);
    a2n = *(const float4*)(arow1 + kn);
    a3n = *(const float4*)(arow1 + kn + 4);
#pragma unroll
    for (int t = 0; t < 6; ++t) bn[t] = *(const short8*)(brow[t] + kn);

    short8 af0, af1;
    af0[0] = (short)f2bf(a0.x); af0[1] = (short)f2bf(a0.y);
    af0[2] = (short)f2bf(a0.z); af0[3] = (short)f2bf(a0.w);
    af0[4] = (short)f2bf(a1.x); af0[5] = (short)f2bf(a1.y);
    af0[6] = (short)f2bf(a1.z); af0[7] = (short)f2bf(a1.w);
    af1[0] = (short)f2bf(a2.x); af1[1] = (short)f2bf(a2.y);
    af1[2] = (short)f2bf(a2.z); af1[3] = (short)f2bf(a2.w);
    af1[4] = (short)f2bf(a3.x); af1[5] = (short)f2bf(a3.y);
    af1[6] = (short)f2bf(a3.z); af1[7] = (short)f2bf(a3.w);

#pragma unroll
    for (int t = 0; t < 6; ++t) {
      acc[0][t] = __builtin_amdgcn_mfma_f32_16x16x32_bf16(af0, bc[t], acc[0][t], 0, 0, 0);
      acc[1][t] = __builtin_amdgcn_mfma_f32_16x16x32_bf16(af1, bc[t], acc[1][t], 0, 0, 0);
    }
  }

  // store split-K partial: C/D layout col=lane&15, row=quad*4+reg (verified)
  float* cpd = cp + ((size_t)sp * NN + m0) * C96;
#pragma unroll
  for (int tile = 0; tile < 2; ++tile)
#pragma unroll
    for (int t = 0; t < 6; ++t) {
      int col = t * 16 + m;
#pragma unroll
      for (int r = 0; r < 4; ++r) {
        int row = tile * 16 + quad * 4 + r;
        cpd[(size_t)row * C96 + col] = acc[tile][t][r];
      }
    }
}

// ---------------------------------------------------------------------------
// Epilogue: sum split-K partials, apply W[48x16] + bias, write out[2][N][16].
// ---------------------------------------------------------------------------
__global__ __launch_bounds__(256) void epilogue(const float* __restrict__ cp,
                                                const float* __restrict__ w,
                                                const float* __restrict__ bias,
                                                float* __restrict__ out) {
  __shared__ float lds_c[64 * 97];
  __shared__ float lds_w[48 * 16];
  __shared__ float lds_bias[16];
  const int tid = threadIdx.x;
  const int n0 = blockIdx.x * 64;

  for (int i = tid; i < 768; i += 256) lds_w[i] = w[i];
  if (tid < 16) lds_bias[tid] = bias[tid];

  const size_t base = (size_t)n0 * C96;
#pragma unroll
  for (int i = 0; i < 24; ++i) {
    int e = tid + i * 256;   // 0..6143 over [64 x 96]
    float s = 0.f;
#pragma unroll
    for (int sp = 0; sp < SPLITK; ++sp)
      s += cp[(size_t)sp * ((size_t)NN * C96) + base + e];
    lds_c[e + e / 96] = s;
  }
  __syncthreads();

  const int node = tid >> 2;
  const int b = (tid >> 1) & 1;
  const int o0 = (tid & 1) * 8;
  const float* crow = &lds_c[node * 97 + b * 48];
  float accv[8];
#pragma unroll
  for (int o = 0; o < 8; ++o) accv[o] = lds_bias[o0 + o];
#pragma unroll
  for (int j = 0; j < 48; ++j) {
    float cv = crow[j];
#pragma unroll
    for (int o = 0; o < 8; ++o) accv[o] += cv * lds_w[j * 16 + o0 + o];
  }
  size_t ob = (size_t)b * ((size_t)NN * OUTD) + (size_t)(n0 + node) * OUTD + o0;
  float4 v0 = {accv[0], accv[1], accv[2], accv[3]};
  float4 v1 = {accv[4], accv[5], accv[6], accv[7]};
  *(float4*)(out + ob) = v0;
  *(float4*)(out + ob + 4) = v1;
}

extern "C" void kernel_launch(void* const* d_in, const int* in_sizes, int n_in,
                              void* d_out, int out_size, void* d_ws, size_t ws_size,
                              hipStream_t stream) {
  (void)in_sizes; (void)n_in; (void)out_size; (void)ws_size;
  const float* inp = (const float*)d_in[0];   // [2,16384,32]
  const float* hid = (const float*)d_in[1];   // [2,16384*16]
  const float* lap = (const float*)d_in[2];   // [16384,16384]
  const float* wts = (const float*)d_in[3];   // [48,16]
  const float* bia = (const float*)d_in[4];   // [16]
  float* out = (float*)d_out;                 // [2,16384*16]

  unsigned short* xt = (unsigned short*)d_ws;             // 3 MB bf16
  float* cp = (float*)((char*)d_ws + (4u << 20));         // 25.2 MB fp32

  prep_xt<<<NN / 64, 256, 0, stream>>>(inp, hid, xt);
  spmm_main<<<NN / 128 * SPLITK, 256, 0, stream>>>(lap, xt, cp);
  epilogue<<<NN / 64, 256, 0, stream>>>(cp, wts, bia, out);
}

// Round 3
// 1375.839 us; speedup vs baseline: 1.0485x; 1.0485x over previous
//
#include <hip/hip_runtime.h>
#include <hip/hip_bf16.h>

// TGCN graph convolution: out = (L @ [inputs|hidden]) @ W + b
// N=16384, B=2, F=32, G=16, OUT=16.
// Round 3: L is ~1% sparse with EXACT zeros (D^-1/2 (A+I) D^-1/2). Stream L
// once (1.07 GB, the true HBM floor ~170us), ballot-scan for nonzeros, and
// for each nonzero k do C[m,:96] += L[m,k] * X[k,:96] wave-parallel (lane j
// owns cols 2j,2j+1; X as packed bf16 pairs, 3.1 MB -> L2-resident).
// No MFMA, no LDS tiles, no barriers, no split-K partial traffic.
// Workspace: xpb (packed bf16 X) 3.1 MB @ ws+0, crow fp32 [N][96] @ ws+4MB.

#define NN   16384
#define FF   32
#define GG   16
#define OUTD 16
#define C96  96

__device__ __forceinline__ unsigned int pack_bf2(float lo, float hi) {
  unsigned short a = __builtin_bit_cast(unsigned short, __float2bfloat16(lo));
  unsigned short b = __builtin_bit_cast(unsigned short, __float2bfloat16(hi));
  return (unsigned int)a | ((unsigned int)b << 16);
}

// ---------------------------------------------------------------------------
// Prep: xpb[k][48] uint, pair c2 holds bf16(cat[k][2*c2]), bf16(cat[k][2*c2+1])
// cat col layout: [0:32)=inp[0][k], [32:48)=hid[0][k], [48:80)=inp[1][k],
// [80:96)=hid[1][k].  One uint4 (4 pairs = 8 cols) per thread, coalesced.
// ---------------------------------------------------------------------------
__global__ __launch_bounds__(256) void prep_xp(const float* __restrict__ inp,
                                               const float* __restrict__ hid,
                                               unsigned int* __restrict__ xpb) {
  int gid = blockIdx.x * 256 + threadIdx.x;   // 16384*12 units
  int k = gid / 12;
  int j = gid - k * 12;
  const float* src;
  if (j < 4)       src = inp + (size_t)k * FF + 8 * j;
  else if (j < 6)  src = hid + (size_t)k * GG + 8 * (j - 4);
  else if (j < 10) src = inp + ((size_t)NN + k) * FF + 8 * (j - 6);
  else             src = hid + ((size_t)NN + k) * GG + 8 * (j - 10);
  float4 v0 = *(const float4*)src;
  float4 v1 = *(const float4*)(src + 4);
  uint4 o;
  o.x = pack_bf2(v0.x, v0.y);
  o.y = pack_bf2(v0.z, v0.w);
  o.z = pack_bf2(v1.x, v1.y);
  o.w = pack_bf2(v1.z, v1.w);
  ((uint4*)xpb)[gid] = o;
}

// ---------------------------------------------------------------------------
// Main: sparse scan. Block owns 8 rows, wave owns 2. Per row: 32 steps of
// 2 KB (lane reads 8 consecutive floats), 8 ballots/step, serial bit-loop
// over nonzeros (expected ~0.7/ballot). Lane j<48 accumulates cols 2j,2j+1.
// ---------------------------------------------------------------------------
__global__ __launch_bounds__(256) void spmm_sparse(const float* __restrict__ L,
                                                   const unsigned int* __restrict__ xpb,
                                                   float* __restrict__ crow) {
  const int lane = threadIdx.x & 63;
  const int wave = threadIdx.x >> 6;
  const int cl = lane < 48 ? lane : lane - 48;   // lanes 48-63 duplicate; never stored

#pragma unroll
  for (int r = 0; r < 2; ++r) {
    const int m = blockIdx.x * 8 + wave * 2 + r;
    const float4* lrow = (const float4*)(L + (size_t)m * NN);
    float accx = 0.f, accy = 0.f;

    int idx = lane * 2;
    float4 c0 = lrow[idx];
    float4 c1 = lrow[idx + 1];

    for (int step = 0; step < 32; ++step) {
      int nidx = (step < 31) ? idx + 128 : lane * 2;   // last prefetch harmless
      float4 n0 = lrow[nidx];
      float4 n1 = lrow[nidx + 1];
      const int kstep = step * 512;

#pragma unroll
      for (int s = 0; s < 8; ++s) {
        float v;
        switch (s) {
          case 0: v = c0.x; break; case 1: v = c0.y; break;
          case 2: v = c0.z; break; case 3: v = c0.w; break;
          case 4: v = c1.x; break; case 5: v = c1.y; break;
          case 6: v = c1.z; break; default: v = c1.w; break;
        }
        unsigned long long msk = __ballot(v != 0.0f);
        while (msk) {
          int b = __builtin_ctzll(msk);
          msk &= msk - 1;
          float val = __shfl(v, b);
          int k = kstep + 8 * b + s;
          unsigned int u = xpb[(size_t)k * 48 + cl];
          float x0 = __builtin_bit_cast(float, u << 16);
          float x1 = __builtin_bit_cast(float, u & 0xffff0000u);
          accx += val * x0;
          accy += val * x1;
        }
      }
      c0 = n0; c1 = n1; idx = nidx;
    }

    if (lane < 48) {
      float2 o = {accx, accy};
      *(float2*)(crow + (size_t)m * C96 + 2 * lane) = o;
    }
  }
}

// ---------------------------------------------------------------------------
// Epilogue: out[b][n][:16] = crow[n][b*48:(b+1)*48] @ W + bias.
// ---------------------------------------------------------------------------
__global__ __launch_bounds__(256) void epilogue(const float* __restrict__ cp,
                                                const float* __restrict__ w,
                                                const float* __restrict__ bias,
                                                float* __restrict__ out) {
  __shared__ float lds_c[64 * 97];
  __shared__ float lds_w[48 * 16];
  __shared__ float lds_bias[16];
  const int tid = threadIdx.x;
  const int n0 = blockIdx.x * 64;

  for (int i = tid; i < 768; i += 256) lds_w[i] = w[i];
  if (tid < 16) lds_bias[tid] = bias[tid];

  const size_t base = (size_t)n0 * C96;
#pragma unroll
  for (int i = 0; i < 24; ++i) {
    int e = tid + i * 256;   // 0..6143 over [64 x 96]
    lds_c[e + e / 96] = cp[base + e];
  }
  __syncthreads();

  const int node = tid >> 2;
  const int b = (tid >> 1) & 1;
  const int o0 = (tid & 1) * 8;
  const float* crow_l = &lds_c[node * 97 + b * 48];
  float accv[8];
#pragma unroll
  for (int o = 0; o < 8; ++o) accv[o] = lds_bias[o0 + o];
#pragma unroll
  for (int j = 0; j < 48; ++j) {
    float cv = crow_l[j];
#pragma unroll
    for (int o = 0; o < 8; ++o) accv[o] += cv * lds_w[j * 16 + o0 + o];
  }
  size_t ob = (size_t)b * ((size_t)NN * OUTD) + (size_t)(n0 + node) * OUTD + o0;
  float4 v0 = {accv[0], accv[1], accv[2], accv[3]};
  float4 v1 = {accv[4], accv[5], accv[6], accv[7]};
  *(float4*)(out + ob) = v0;
  *(float4*)(out + ob + 4) = v1;
}

extern "C" void kernel_launch(void* const* d_in, const int* in_sizes, int n_in,
                              void* d_out, int out_size, void* d_ws, size_t ws_size,
                              hipStream_t stream) {
  (void)in_sizes; (void)n_in; (void)out_size; (void)ws_size;
  const float* inp = (const float*)d_in[0];   // [2,16384,32]
  const float* hid = (const float*)d_in[1];   // [2,16384*16]
  const float* lap = (const float*)d_in[2];   // [16384,16384]
  const float* wts = (const float*)d_in[3];   // [48,16]
  const float* bia = (const float*)d_in[4];   // [16]
  float* out = (float*)d_out;                 // [2,16384*16]

  unsigned int* xpb = (unsigned int*)d_ws;                 // 3.1 MB packed bf16
  float* crow = (float*)((char*)d_ws + (4u << 20));        // 6.3 MB fp32

  prep_xp<<<(NN * 12) / 256, 256, 0, stream>>>(inp, hid, xpb);
  spmm_sparse<<<NN / 8, 256, 0, stream>>>(lap, xpb, crow);
  epilogue<<<NN / 64, 256, 0, stream>>>(crow, wts, bia, out);
}